// Round 10
// baseline (256.403 us; speedup 1.0000x reference)
//
#include <hip/hip_runtime.h>

#define NEGINF (-1e30f)

// ---------------- problem constants ----------------
// b=4, c=64, h=w=5, q=75, u=100, N_WAY=5, K_SHOT=5
// M_s = 125 (per way), M_u = 2500, M_q = 25, M_tot = 2625
// ---------------- workspace layout (float units) ----------------
constexpr size_t OF_UNL  = 0;                              // [4][2500][64]
constexpr size_t OF_SUP  = OF_UNL  + (size_t)4*2500*64;    // [4][5][125][64]
constexpr size_t OF_SUPT = OF_SUP  + (size_t)4*5*125*64;   // [4][5][64][128]
constexpr size_t OF_QT   = OF_SUPT + (size_t)4*5*64*128;   // [300][16cg][25mq][4c]  scalar-load-friendly
constexpr size_t OF_ROWV = OF_QT   + (size_t)300*64*25;    // [4][5][8ck][2500] f
constexpr size_t OF_ROWI = OF_ROWV + (size_t)4*5*8*2500;   // [4][5][8ck][2500] i
constexpr size_t OF_CVI  = OF_ROWI + (size_t)4*5*8*2500;   // [4][5][125][20][2]
constexpr size_t OF_CMP  = OF_CVI  + (size_t)4*5*125*20*2; // [4][5][2500] i
constexpr size_t OF_CNT  = OF_CMP  + (size_t)4*5*2500;     // [20] i
constexpr size_t OF_UNEAR= OF_CNT  + 20;                   // [4][2500] i
constexpr size_t OF_SNEAR= OF_UNEAR+ 10000;                // [4][625]  i
constexpr size_t OF_BV   = OF_SNEAR+ 2500;                 // [300][5][25] f
constexpr size_t OF_BP   = OF_BV   + 37500;                // [300][5][25] i
constexpr size_t OF_AMX  = OF_BP   + 37500;                // [300][3200] u8

// ============================================================
// Kernel A: L2-normalize all three tensors into ws layouts.
// Query written [bq][cg][mq][4]: each (cg,mq) float-quad contiguous,
// address block-uniform in kc1 -> eligible for s_load promotion.
// ============================================================
__global__ __launch_bounds__(256) void knorm(
    const float* __restrict__ sup, const float* __restrict__ qry,
    const float* __restrict__ unl,
    float* __restrict__ unl_n, float* __restrict__ sup_n,
    float* __restrict__ supT, float* __restrict__ qt)
{
    int gid = blockIdx.x * 256 + threadIdx.x;
    int loc = gid >> 4;
    int sub = gid & 15;
    if (loc >= 20000) return;

    const float* src;
    float* dst1; int q_mode = 0;
    float* dst2 = nullptr;
    int qmq = 0;

    if (loc < 10000) {
        int b = loc / 2500, m = loc % 2500;
        int u = m / 25, hw = m % 25;
        src  = unl + ((size_t)(b*100 + u) * 64) * 25 + hw;
        dst1 = unl_n + (size_t)loc * 64;
    } else if (loc < 12500) {
        int idx = loc - 10000;
        int b = idx / 625, r = idx % 625;
        int w = r / 125,  n = r % 125;
        int shot = n / 25, hw = n % 25;
        src  = sup + ((size_t)(b*25 + w*5 + shot) * 64) * 25 + hw;
        dst1 = sup_n + (size_t)idx * 64;
        dst2 = supT + ((size_t)(b*5 + w) * 64) * 128 + n;
    } else {
        int idx = loc - 12500;
        int bq = idx / 25; qmq = idx % 25;
        src  = qry + ((size_t)bq * 64) * 25 + qmq;
        dst1 = qt + (size_t)bq * 1600;   // base; indexed per cg below
        q_mode = 1;
    }

    float v[4]; float ss = 0.f;
    int c0 = sub * 4;
#pragma unroll
    for (int j = 0; j < 4; ++j) { v[j] = src[(size_t)(c0 + j) * 25]; ss += v[j] * v[j]; }
#pragma unroll
    for (int msk = 1; msk < 16; msk <<= 1) ss += __shfl_xor(ss, msk);
    float sc = 1.f / fmaxf(sqrtf(ss), 1e-12f);
#pragma unroll
    for (int j = 0; j < 4; ++j) {
        float o = v[j] * sc;
        if (q_mode) dst1[sub * 100 + qmq * 4 + j] = o;   // [cg=sub][mq][4]
        else        dst1[c0 + j] = o;
        if (dst2) dst2[(size_t)(c0 + j) * 128] = o;
    }
}

// ============================================================
// Kernel B: u2s pass. 1600 blocks x 256 threads.
// (unchanged — LDS-staged sup tile, broadcast reads)
// ============================================================
__global__ __launch_bounds__(256) void kb(
    const float* __restrict__ unl_n, const float* __restrict__ supT,
    float* __restrict__ rowv, int* __restrict__ rowi, float* __restrict__ colvi)
{
    int bid = blockIdx.x;
    int nc = bid & 3;
    int mb = (bid >> 2) % 20;
    int bw = bid / 80;               // b*5+w
    int b  = bw / 5;
    int tid = threadIdx.x;
    int lane = tid & 63, wv = tid >> 6;

    __shared__ float uls[128 * 65];
    __shared__ float sls[64 * 36];
    __shared__ float sv_[4][32];
    __shared__ int   si_[4][32];

    int m0 = mb * 128;
    int n0 = nc * 32;

    for (int i = tid; i < 128 * 16; i += 256) {
        int row = i >> 4, c4 = (i & 15) * 4;
        int m = m0 + row;
        float4 x = make_float4(0.f, 0.f, 0.f, 0.f);
        if (m < 2500) x = *(const float4*)(unl_n + ((size_t)(b * 2500 + m)) * 64 + c4);
        uls[row * 65 + c4 + 0] = x.x;
        uls[row * 65 + c4 + 1] = x.y;
        uls[row * 65 + c4 + 2] = x.z;
        uls[row * 65 + c4 + 3] = x.w;
    }
    {
        int c = tid >> 2, q = tid & 3;
        const float* sp = supT + ((size_t)bw * 64 + c) * 128 + n0 + q * 8;
        float4 a = *(const float4*)sp;
        float4 d4 = *(const float4*)(sp + 4);
        float* d = &sls[c * 36 + q * 8];
        d[0] = a.x; d[1] = a.y; d[2] = a.z; d[3] = a.w;
        d[4] = d4.x; d[5] = d4.y; d[6] = d4.z; d[7] = d4.w;
    }
    __syncthreads();

    int ml = tid & 127;
    int m  = m0 + ml;
    int nh = tid >> 7;
    int nbase = nh * 16;
    int nn_total = (125 - n0) < 32 ? (125 - n0) : 32;
    const float* myrow = &uls[ml * 65];

    float acc[16];
#pragma unroll
    for (int j = 0; j < 16; ++j) acc[j] = 0.f;

    for (int c = 0; c < 64; ++c) {
        float uv = myrow[c];
        const float4* sr = (const float4*)&sls[c * 36 + nbase];
        float4 s0 = sr[0], s1 = sr[1], s2 = sr[2], s3 = sr[3];
        acc[0]  = fmaf(uv, s0.x, acc[0]);  acc[1]  = fmaf(uv, s0.y, acc[1]);
        acc[2]  = fmaf(uv, s0.z, acc[2]);  acc[3]  = fmaf(uv, s0.w, acc[3]);
        acc[4]  = fmaf(uv, s1.x, acc[4]);  acc[5]  = fmaf(uv, s1.y, acc[5]);
        acc[6]  = fmaf(uv, s1.z, acc[6]);  acc[7]  = fmaf(uv, s1.w, acc[7]);
        acc[8]  = fmaf(uv, s2.x, acc[8]);  acc[9]  = fmaf(uv, s2.y, acc[9]);
        acc[10] = fmaf(uv, s2.z, acc[10]); acc[11] = fmaf(uv, s2.w, acc[11]);
        acc[12] = fmaf(uv, s3.x, acc[12]); acc[13] = fmaf(uv, s3.y, acc[13]);
        acc[14] = fmaf(uv, s3.z, acc[14]); acc[15] = fmaf(uv, s3.w, acc[15]);
    }

    int nnloc = nn_total - nbase;
    nnloc = nnloc < 0 ? 0 : (nnloc > 16 ? 16 : nnloc);
    float rbv = NEGINF; int rbi = 0;
    for (int j = 0; j < nnloc; ++j)
        if (acc[j] > rbv) { rbv = acc[j]; rbi = n0 + nbase + j; }
    if (m < 2500) {
        int ck = nc * 2 + nh;
        rowv[((size_t)bw * 8 + ck) * 2500 + m] = rbv;
        rowi[((size_t)bw * 8 + ck) * 2500 + m] = rbi;
    }

#pragma unroll
    for (int j = 0; j < 16; ++j) {
        float v = (m < 2500 && (nbase + j) < nn_total) ? acc[j] : NEGINF;
        float vm = v;
#pragma unroll
        for (int s2 = 1; s2 < 64; s2 <<= 1) vm = fmaxf(vm, __shfl_xor(vm, s2));
        unsigned long long msk = __ballot(v == vm);
        int first = __ffsll((unsigned long long)msk) - 1;
        if (lane == 0) { sv_[wv][nbase + j] = vm; si_[wv][nbase + j] = m0 + (wv & 1) * 64 + first; }
    }
    __syncthreads();
    if (tid < nn_total) {
        int w0 = (tid < 16) ? 0 : 2;
        float v = sv_[w0][tid];     int vi = si_[w0][tid];
        float v2 = sv_[w0 + 1][tid]; int i2 = si_[w0 + 1][tid];
        if (v2 > v || (v2 == v && i2 < vi)) { v = v2; vi = i2; }
        float* cv = colvi + ((((size_t)bw) * 125 + (n0 + tid)) * 20 + mb) * 2;
        cv[0] = v; ((int*)cv)[1] = vi;
    }
}

// ============================================================
// Kernel M: merge row partials -> unear, col partials -> snear.
// ============================================================
__global__ __launch_bounds__(256) void kmerge(
    const float* __restrict__ rowv, const int* __restrict__ rowi,
    const float* __restrict__ colvi,
    int* __restrict__ unear, int* __restrict__ snear)
{
    int it = blockIdx.x * 256 + threadIdx.x;
    if (it < 10000) {
        int b = it / 2500, m = it % 2500;
        float bv = NEGINF; int bi = 0;
#pragma unroll
        for (int w = 0; w < 5; ++w) {
#pragma unroll
            for (int ck = 0; ck < 8; ++ck) {
                size_t o = (((size_t)(b * 5 + w)) * 8 + ck) * 2500 + m;
                float v = rowv[o];
                if (v > bv) { bv = v; bi = w * 125 + rowi[o]; }
            }
        }
        unear[it] = bi;
    } else if (it < 12500) {
        int idx = it - 10000;
        const float* p = colvi + (size_t)idx * 40;
        float bv = NEGINF; int bi = 0x7fffffff;
        for (int mb2 = 0; mb2 < 20; ++mb2) {
            float v = p[mb2 * 2]; int vi = ((const int*)p)[mb2 * 2 + 1];
            if (v > bv || (v == bv && vi < bi)) { bv = v; bi = vi; }
        }
        snear[idx] = bi;
    }
}

// ============================================================
// Kernel P: mutual-NN mask + stable stream compaction. 20 blocks x 256.
// ============================================================
__global__ __launch_bounds__(256) void kcmp(
    const int* __restrict__ unear, const int* __restrict__ snear,
    int* __restrict__ cmp, int* __restrict__ cntg)
{
    int p = blockIdx.x;
    int b = p / 5, way = p % 5;
    int tid = threadIdx.x, lane = tid & 63, wv = tid >> 6;
    __shared__ unsigned long long masks[40];
    __shared__ int base[40];

    for (int ch = wv; ch < 40; ch += 4) {
        int m = ch * 64 + lane;
        bool ok = false;
        if (m < 2500) {
            int un = unear[b * 2500 + m];
            ok = (un / 125 == way) && (snear[b * 625 + un] == m);
        }
        unsigned long long msk = __ballot(ok ? 1 : 0);
        if (lane == 0) masks[ch] = msk;
    }
    __syncthreads();
    if (tid == 0) {
        int s = 0;
        for (int ch = 0; ch < 40; ++ch) { base[ch] = s; s += __popcll(masks[ch]); }
        cntg[p] = s;
    }
    __syncthreads();
    for (int ch = wv; ch < 40; ch += 4) {
        unsigned long long msk = masks[ch];
        if ((msk >> lane) & 1ull) {
            int pre = __popcll(msk & ((1ull << lane) - 1ull));
            cmp[(size_t)p * 2500 + base[ch] + pre] = ch * 64 + lane;
        }
    }
}

// ============================================================
// Kernel C1: query similarity, one block (256 thr) per (bq, way).
// Round-9 fix: r8's LDS q-staging made kc1 LDS-ISSUE bound (400
// uniform ds_read_b128/column x 12 cyc = 4800 cyc > 3200 FMA cyc;
// predicted 47 us == measured 48). q now read from GLOBAL in the
// [cg][mq][4] layout with block-uniform addresses, executed
// UNCONDITIONALLY (no divergent guard) -> compiler can promote to
// s_load (scalar path: no LDS, no vector-VMEM cost). Column index is
// clamped for n >= cw (compute garbage, stores guarded).
// ============================================================
__global__ __launch_bounds__(256) void kc1(
    const float* __restrict__ qt, const float* __restrict__ sup_n,
    const float* __restrict__ unl_n, const int* __restrict__ cmp,
    const int* __restrict__ cntg,
    float* __restrict__ bvg, int* __restrict__ bpg,
    unsigned char* __restrict__ amaxg)
{
    int bid = blockIdx.x;
    int w = bid % 5, bq = bid / 5;
    int b = bq / 75;
    int tid = threadIdx.x;

    const float* qtb = qt + (size_t)bq * 1600;   // [cg][mq][4]

    int L = 0;
#pragma unroll
    for (int i = 0; i < 20; ++i) { int v = cntg[i]; L = L > v ? L : v; }
    int cntw = 0, wb = 0;
#pragma unroll
    for (int w2 = 0; w2 < 5; ++w2) {
        int c2 = cntg[b * 5 + w2];
        if (w2 < w) wb += 125 + c2;
        if (w2 == w) cntw = c2;
    }
    int cw = 125 + cntw;    // 125 <= cw <= 250, so one 256-col pass covers it

    __shared__ float simb[25 * 257];
    __shared__ float redv[8][25];
    __shared__ int   redp[8][25];

    int rg = tid / 25, rq = tid % 25;
    float bv1 = NEGINF; int bp1 = 0x7fffffff;

    {
        int n = tid;
        int nn = n < cw ? n : cw - 1;    // clamp: all threads compute (valid mem)
        const float* colp;
        if (nn < 125) colp = sup_n + (((size_t)(b * 5 + w)) * 125 + nn) * 64;
        else {
            int m = cmp[((size_t)(b * 5 + w)) * 2500 + (nn - 125)];
            colp = unl_n + ((size_t)(b * 2500 + m)) * 64;
        }
        float acc[25];
#pragma unroll
        for (int i = 0; i < 25; ++i) acc[i] = 0.f;
#pragma unroll
        for (int cg = 0; cg < 16; ++cg) {
            float4 cv = *(const float4*)(colp + cg * 4);        // per-lane VMEM
            const float* qcg = qtb + cg * 100;                  // block-uniform
#pragma unroll
            for (int mq = 0; mq < 25; ++mq) {
                float4 qv = *(const float4*)(qcg + mq * 4);     // uniform -> s_load
                acc[mq] = fmaf(cv.x, qv.x, acc[mq]);
                acc[mq] = fmaf(cv.y, qv.y, acc[mq]);
                acc[mq] = fmaf(cv.z, qv.z, acc[mq]);
                acc[mq] = fmaf(cv.w, qv.w, acc[mq]);
            }
        }
        float cmax = NEGINF; int cam = 0;
#pragma unroll
        for (int mq = 0; mq < 25; ++mq) {
            float s = (acc[mq] + 1.0f) * 0.5f;
            if (s > cmax) { cmax = s; cam = mq; }
            if (n < cw) simb[mq * 257 + tid] = s;
        }
        if (n < cw) amaxg[(size_t)bq * 3200 + (wb + n)] = (unsigned char)cam;
    }
    __syncthreads();
    if (tid < 200) {
        int base = rg * 32;
        for (int i = 0; i < 32; ++i) {
            int n2 = base + i;
            if (n2 < cw) {
                float s = simb[rq * 257 + n2];
                if (s > bv1) { bv1 = s; bp1 = ((w * 2625 + n2) << 12) | (wb + n2); }
            }
        }
        redv[rg][rq] = bv1; redp[rg][rq] = bp1;
    }
    __syncthreads();
    if (tid < 25) {
        float v = redv[0][tid]; int p = redp[0][tid];
#pragma unroll
        for (int g = 1; g < 8; ++g)
            if (redv[g][tid] > v) { v = redv[g][tid]; p = redp[g][tid]; }
        if (L > cntw) {
            int pp = ((w * 2625 + 125 + cntw) << 12) | 0xFFF;
            if (0.5f > v || (0.5f == v && pp < p)) { v = 0.5f; p = pp; }
        }
        size_t o = ((size_t)bq * 5 + w) * 25 + tid;
        bvg[o] = v; bpg[o] = p;
    }
}

// ============================================================
// Kernel CE: merge 5 way-partials per (bq,mq), mutual mask, row loss,
// atomicAdd into d_out. 300 blocks x 64.
// ============================================================
__global__ __launch_bounds__(64) void kce(
    const float* __restrict__ bvg, const int* __restrict__ bpg,
    const unsigned char* __restrict__ amaxg, const int* __restrict__ qy,
    float* __restrict__ out)
{
    int bq = blockIdx.x;
    int tid = threadIdx.x;
    __shared__ float qmask[25];
    __shared__ float lg[5];
    if (tid < 25) {
        float v = NEGINF; int p = 0x7fffffff;
#pragma unroll
        for (int w = 0; w < 5; ++w) {
            size_t o = ((size_t)bq * 5 + w) * 25 + tid;
            float v2 = bvg[o]; int p2 = bpg[o];
            if (v2 > v || (v2 == v && p2 < p)) { v = v2; p = p2; }
        }
        int pos = p & 0xFFF;
        int g = (pos == 0xFFF) ? 0 : (int)amaxg[(size_t)bq * 3200 + pos];
        qmask[tid] = (g == tid) ? 1.0f : 0.0f;
    }
    __syncthreads();
    if (tid < 5) {
        float s = 0.f;
#pragma unroll
        for (int mq = 0; mq < 25; ++mq)
            s += bvg[((size_t)bq * 5 + tid) * 25 + mq] * qmask[mq];
        lg[tid] = s;
    }
    __syncthreads();
    if (tid == 0) {
        int y = qy[bq];
        float mx = lg[0];
#pragma unroll
        for (int w = 1; w < 5; ++w) mx = fmaxf(mx, lg[w]);
        float se = 0.f;
#pragma unroll
        for (int w = 0; w < 5; ++w) se += expf(lg[w] - mx);
        float loss = -(lg[y] - mx - logf(se));
        atomicAdd(out, loss * (1.0f / 300.0f));
    }
}

// ============================================================
extern "C" void kernel_launch(void* const* d_in, const int* in_sizes, int n_in,
                              void* d_out, int out_size, void* d_ws, size_t ws_size,
                              hipStream_t stream)
{
    const float* sup = (const float*)d_in[0];
    const float* qry = (const float*)d_in[2];
    const int*   qy  = (const int*)d_in[3];
    const float* unl = (const float*)d_in[4];

    float* ws    = (float*)d_ws;
    float* unl_n = ws + OF_UNL;
    float* sup_n = ws + OF_SUP;
    float* supT  = ws + OF_SUPT;
    float* qt    = ws + OF_QT;
    float* rowv  = ws + OF_ROWV;
    int*   rowi  = (int*)(ws + OF_ROWI);
    float* colvi = ws + OF_CVI;
    int*   cmp   = (int*)(ws + OF_CMP);
    int*   cntg  = (int*)(ws + OF_CNT);
    int*   unear = (int*)(ws + OF_UNEAR);
    int*   snear = (int*)(ws + OF_SNEAR);
    float* bvg   = ws + OF_BV;
    int*   bpg   = (int*)(ws + OF_BP);
    unsigned char* amaxg = (unsigned char*)(ws + OF_AMX);

    hipMemsetAsync(d_out, 0, sizeof(float), stream);

    hipLaunchKernelGGL(knorm, dim3(1250), dim3(256), 0, stream,
                       sup, qry, unl, unl_n, sup_n, supT, qt);
    hipLaunchKernelGGL(kb, dim3(1600), dim3(256), 0, stream,
                       unl_n, supT, rowv, rowi, colvi);
    hipLaunchKernelGGL(kmerge, dim3(49), dim3(256), 0, stream,
                       rowv, rowi, colvi, unear, snear);
    hipLaunchKernelGGL(kcmp, dim3(20), dim3(256), 0, stream,
                       unear, snear, cmp, cntg);
    hipLaunchKernelGGL(kc1, dim3(1500), dim3(256), 0, stream,
                       qt, sup_n, unl_n, cmp, cntg, bvg, bpg, amaxg);
    hipLaunchKernelGGL(kce, dim3(300), dim3(64), 0, stream,
                       bvg, bpg, amaxg, qy, (float*)d_out);
}

// Round 11
// 220.925 us; speedup vs baseline: 1.1606x; 1.1606x over previous
//
#include <hip/hip_runtime.h>

#define NEGINF (-1e30f)

// ---------------- problem constants ----------------
// b=4, c=64, h=w=5, q=75, u=100, N_WAY=5, K_SHOT=5
// M_s = 125 (per way), M_u = 2500, M_q = 25, M_tot = 2625
// ---------------- workspace layout (float units) ----------------
constexpr size_t OF_UNL  = 0;                              // [4][2500][64]
constexpr size_t OF_SUP  = OF_UNL  + (size_t)4*2500*64;    // [4][5][125][64]
constexpr size_t OF_SUPT = OF_SUP  + (size_t)4*5*125*64;   // [4][5][64][128]
constexpr size_t OF_QT   = OF_SUPT + (size_t)4*5*64*128;   // [300][25mq][64c]
constexpr size_t OF_ROWV = OF_QT   + (size_t)300*64*25;    // [4][5][8ck][2500] f
constexpr size_t OF_ROWI = OF_ROWV + (size_t)4*5*8*2500;   // [4][5][8ck][2500] i
constexpr size_t OF_CVI  = OF_ROWI + (size_t)4*5*8*2500;   // [4][5][125][20][2]
constexpr size_t OF_CMP  = OF_CVI  + (size_t)4*5*125*20*2; // [4][5][2500] i
constexpr size_t OF_CNT  = OF_CMP  + (size_t)4*5*2500;     // [20] i
constexpr size_t OF_UNEAR= OF_CNT  + 20;                   // [4][2500] i
constexpr size_t OF_SNEAR= OF_UNEAR+ 10000;                // [4][625]  i
constexpr size_t OF_BV   = OF_SNEAR+ 2500;                 // [300][5][25] f
constexpr size_t OF_BP   = OF_BV   + 37500;                // [300][5][25] i
constexpr size_t OF_AMX  = OF_BP   + 37500;                // [300][3200] u8

// ============================================================
// Kernel A: L2-normalize all three tensors into ws layouts.
// Query written [bq][mq][64] (stride-1 coalesced; staged by kc1).
// ============================================================
__global__ __launch_bounds__(256) void knorm(
    const float* __restrict__ sup, const float* __restrict__ qry,
    const float* __restrict__ unl,
    float* __restrict__ unl_n, float* __restrict__ sup_n,
    float* __restrict__ supT, float* __restrict__ qt)
{
    int gid = blockIdx.x * 256 + threadIdx.x;
    int loc = gid >> 4;
    int sub = gid & 15;
    if (loc >= 20000) return;

    const float* src;
    float* dst1;
    float* dst2 = nullptr;

    if (loc < 10000) {
        int b = loc / 2500, m = loc % 2500;
        int u = m / 25, hw = m % 25;
        src  = unl + ((size_t)(b*100 + u) * 64) * 25 + hw;
        dst1 = unl_n + (size_t)loc * 64;
    } else if (loc < 12500) {
        int idx = loc - 10000;
        int b = idx / 625, r = idx % 625;
        int w = r / 125,  n = r % 125;
        int shot = n / 25, hw = n % 25;
        src  = sup + ((size_t)(b*25 + w*5 + shot) * 64) * 25 + hw;
        dst1 = sup_n + (size_t)idx * 64;
        dst2 = supT + ((size_t)(b*5 + w) * 64) * 128 + n;
    } else {
        int idx = loc - 12500;
        int bq = idx / 25, mq = idx % 25;
        src  = qry + ((size_t)bq * 64) * 25 + mq;
        dst1 = qt + ((size_t)bq * 25 + mq) * 64;   // [bq][mq][c]
    }

    float v[4]; float ss = 0.f;
    int c0 = sub * 4;
#pragma unroll
    for (int j = 0; j < 4; ++j) { v[j] = src[(size_t)(c0 + j) * 25]; ss += v[j] * v[j]; }
#pragma unroll
    for (int msk = 1; msk < 16; msk <<= 1) ss += __shfl_xor(ss, msk);
    float sc = 1.f / fmaxf(sqrtf(ss), 1e-12f);
#pragma unroll
    for (int j = 0; j < 4; ++j) {
        float o = v[j] * sc;
        dst1[c0 + j] = o;
        if (dst2) dst2[(size_t)(c0 + j) * 128] = o;
    }
}

// ============================================================
// Kernel B: u2s pass. 1600 blocks x 256 threads. (unchanged)
// ============================================================
__global__ __launch_bounds__(256) void kb(
    const float* __restrict__ unl_n, const float* __restrict__ supT,
    float* __restrict__ rowv, int* __restrict__ rowi, float* __restrict__ colvi)
{
    int bid = blockIdx.x;
    int nc = bid & 3;
    int mb = (bid >> 2) % 20;
    int bw = bid / 80;               // b*5+w
    int b  = bw / 5;
    int tid = threadIdx.x;
    int lane = tid & 63, wv = tid >> 6;

    __shared__ float uls[128 * 65];
    __shared__ float sls[64 * 36];
    __shared__ float sv_[4][32];
    __shared__ int   si_[4][32];

    int m0 = mb * 128;
    int n0 = nc * 32;

    for (int i = tid; i < 128 * 16; i += 256) {
        int row = i >> 4, c4 = (i & 15) * 4;
        int m = m0 + row;
        float4 x = make_float4(0.f, 0.f, 0.f, 0.f);
        if (m < 2500) x = *(const float4*)(unl_n + ((size_t)(b * 2500 + m)) * 64 + c4);
        uls[row * 65 + c4 + 0] = x.x;
        uls[row * 65 + c4 + 1] = x.y;
        uls[row * 65 + c4 + 2] = x.z;
        uls[row * 65 + c4 + 3] = x.w;
    }
    {
        int c = tid >> 2, q = tid & 3;
        const float* sp = supT + ((size_t)bw * 64 + c) * 128 + n0 + q * 8;
        float4 a = *(const float4*)sp;
        float4 d4 = *(const float4*)(sp + 4);
        float* d = &sls[c * 36 + q * 8];
        d[0] = a.x; d[1] = a.y; d[2] = a.z; d[3] = a.w;
        d[4] = d4.x; d[5] = d4.y; d[6] = d4.z; d[7] = d4.w;
    }
    __syncthreads();

    int ml = tid & 127;
    int m  = m0 + ml;
    int nh = tid >> 7;
    int nbase = nh * 16;
    int nn_total = (125 - n0) < 32 ? (125 - n0) : 32;
    const float* myrow = &uls[ml * 65];

    float acc[16];
#pragma unroll
    for (int j = 0; j < 16; ++j) acc[j] = 0.f;

    for (int c = 0; c < 64; ++c) {
        float uv = myrow[c];
        const float4* sr = (const float4*)&sls[c * 36 + nbase];
        float4 s0 = sr[0], s1 = sr[1], s2 = sr[2], s3 = sr[3];
        acc[0]  = fmaf(uv, s0.x, acc[0]);  acc[1]  = fmaf(uv, s0.y, acc[1]);
        acc[2]  = fmaf(uv, s0.z, acc[2]);  acc[3]  = fmaf(uv, s0.w, acc[3]);
        acc[4]  = fmaf(uv, s1.x, acc[4]);  acc[5]  = fmaf(uv, s1.y, acc[5]);
        acc[6]  = fmaf(uv, s1.z, acc[6]);  acc[7]  = fmaf(uv, s1.w, acc[7]);
        acc[8]  = fmaf(uv, s2.x, acc[8]);  acc[9]  = fmaf(uv, s2.y, acc[9]);
        acc[10] = fmaf(uv, s2.z, acc[10]); acc[11] = fmaf(uv, s2.w, acc[11]);
        acc[12] = fmaf(uv, s3.x, acc[12]); acc[13] = fmaf(uv, s3.y, acc[13]);
        acc[14] = fmaf(uv, s3.z, acc[14]); acc[15] = fmaf(uv, s3.w, acc[15]);
    }

    int nnloc = nn_total - nbase;
    nnloc = nnloc < 0 ? 0 : (nnloc > 16 ? 16 : nnloc);
    float rbv = NEGINF; int rbi = 0;
    for (int j = 0; j < nnloc; ++j)
        if (acc[j] > rbv) { rbv = acc[j]; rbi = n0 + nbase + j; }
    if (m < 2500) {
        int ck = nc * 2 + nh;
        rowv[((size_t)bw * 8 + ck) * 2500 + m] = rbv;
        rowi[((size_t)bw * 8 + ck) * 2500 + m] = rbi;
    }

#pragma unroll
    for (int j = 0; j < 16; ++j) {
        float v = (m < 2500 && (nbase + j) < nn_total) ? acc[j] : NEGINF;
        float vm = v;
#pragma unroll
        for (int s2 = 1; s2 < 64; s2 <<= 1) vm = fmaxf(vm, __shfl_xor(vm, s2));
        unsigned long long msk = __ballot(v == vm);
        int first = __ffsll((unsigned long long)msk) - 1;
        if (lane == 0) { sv_[wv][nbase + j] = vm; si_[wv][nbase + j] = m0 + (wv & 1) * 64 + first; }
    }
    __syncthreads();
    if (tid < nn_total) {
        int w0 = (tid < 16) ? 0 : 2;
        float v = sv_[w0][tid];     int vi = si_[w0][tid];
        float v2 = sv_[w0 + 1][tid]; int i2 = si_[w0 + 1][tid];
        if (v2 > v || (v2 == v && i2 < vi)) { v = v2; vi = i2; }
        float* cv = colvi + ((((size_t)bw) * 125 + (n0 + tid)) * 20 + mb) * 2;
        cv[0] = v; ((int*)cv)[1] = vi;
    }
}

// ============================================================
// Kernel M: merge row partials -> unear, col partials -> snear.
// ============================================================
__global__ __launch_bounds__(256) void kmerge(
    const float* __restrict__ rowv, const int* __restrict__ rowi,
    const float* __restrict__ colvi,
    int* __restrict__ unear, int* __restrict__ snear)
{
    int it = blockIdx.x * 256 + threadIdx.x;
    if (it < 10000) {
        int b = it / 2500, m = it % 2500;
        float bv = NEGINF; int bi = 0;
#pragma unroll
        for (int w = 0; w < 5; ++w) {
#pragma unroll
            for (int ck = 0; ck < 8; ++ck) {
                size_t o = (((size_t)(b * 5 + w)) * 8 + ck) * 2500 + m;
                float v = rowv[o];
                if (v > bv) { bv = v; bi = w * 125 + rowi[o]; }
            }
        }
        unear[it] = bi;
    } else if (it < 12500) {
        int idx = it - 10000;
        const float* p = colvi + (size_t)idx * 40;
        float bv = NEGINF; int bi = 0x7fffffff;
        for (int mb2 = 0; mb2 < 20; ++mb2) {
            float v = p[mb2 * 2]; int vi = ((const int*)p)[mb2 * 2 + 1];
            if (v > bv || (v == bv && vi < bi)) { bv = v; bi = vi; }
        }
        snear[idx] = bi;
    }
}

// ============================================================
// Kernel P: mutual-NN mask + stable stream compaction. 20 blocks x 256.
// ============================================================
__global__ __launch_bounds__(256) void kcmp(
    const int* __restrict__ unear, const int* __restrict__ snear,
    int* __restrict__ cmp, int* __restrict__ cntg)
{
    int p = blockIdx.x;
    int b = p / 5, way = p % 5;
    int tid = threadIdx.x, lane = tid & 63, wv = tid >> 6;
    __shared__ unsigned long long masks[40];
    __shared__ int base[40];

    for (int ch = wv; ch < 40; ch += 4) {
        int m = ch * 64 + lane;
        bool ok = false;
        if (m < 2500) {
            int un = unear[b * 2500 + m];
            ok = (un / 125 == way) && (snear[b * 625 + un] == m);
        }
        unsigned long long msk = __ballot(ok ? 1 : 0);
        if (lane == 0) masks[ch] = msk;
    }
    __syncthreads();
    if (tid == 0) {
        int s = 0;
        for (int ch = 0; ch < 40; ++ch) { base[ch] = s; s += __popcll(masks[ch]); }
        cntg[p] = s;
    }
    __syncthreads();
    for (int ch = wv; ch < 40; ch += 4) {
        unsigned long long msk = masks[ch];
        if ((msk >> lane) & 1ull) {
            int pre = __popcll(msk & ((1ull << lane) - 1ull));
            cmp[(size_t)p * 2500 + base[ch] + pre] = ch * 64 + lane;
        }
    }
}

// ============================================================
// Kernel C1: query similarity, one block (320 thr = 5 waves) per
// (bq, way). Round-10 restructure: REGISTER-TILED GEMM.
//   wave ty (0..4) owns mqs ty*5..ty*5+4; lane owns cols lane*4..+3.
//   Per c-group of 4: 5 q float4 (LDS, wave-uniform addr -> HW
//   broadcast, ~free) + 4 col float4 (per-lane VMEM) -> 80 FMA.
//   Operand reads/FMA = 0.11 vs 1.0 in all r8-r10 variants (which
//   bounced 44/48/150 us on VMEM-issue / LDS-issue / bad codegen).
// Epilogue: acc -> simb[mq][260] via ds_write_b128 (consecutive
// addr, conflict-free); exact amax/best reduces as before (ascending
// col, strict >). cw <= 250 <= 256 cols -> single pass.
// ============================================================
__global__ __launch_bounds__(320) void kc1(
    const float* __restrict__ qt, const float* __restrict__ sup_n,
    const float* __restrict__ unl_n, const int* __restrict__ cmp,
    const int* __restrict__ cntg,
    float* __restrict__ bvg, int* __restrict__ bpg,
    unsigned char* __restrict__ amaxg)
{
    int bid = blockIdx.x;
    int w = bid % 5, bq = bid / 5;
    int b = bq / 75;
    int tid = threadIdx.x;
    int lane = tid & 63, ty = tid >> 6;

    int L = 0;
#pragma unroll
    for (int i = 0; i < 20; ++i) { int v = cntg[i]; L = L > v ? L : v; }
    int cntw = 0, wb = 0;
#pragma unroll
    for (int w2 = 0; w2 < 5; ++w2) {
        int c2 = cntg[b * 5 + w2];
        if (w2 < w) wb += 125 + c2;
        if (w2 == w) cntw = c2;
    }
    int cw = 125 + cntw;    // 125..250

    __shared__ float qls[25 * 64];       // [mq][c]
    __shared__ float simb[25 * 260];     // [mq][col], b128-aligned stride
    __shared__ float redv[10][25];
    __shared__ int   redp[10][25];

    // stage q tile (coalesced, 1600 floats)
    for (int i = tid; i < 1600; i += 320) qls[i] = qt[(size_t)bq * 1600 + i];

    // column pointers (clamped for col >= cw; stores guarded later)
    int col0 = lane * 4;
    const float* colp0; const float* colp1; const float* colp2; const float* colp3;
    {
        const int* cmpw = cmp + ((size_t)(b * 5 + w)) * 2500;
#define COLPTR(J, DST) { int n = col0 + (J); n = n < cw ? n : cw - 1; \
        if (n < 125) DST = sup_n + (((size_t)(b * 5 + w)) * 125 + n) * 64; \
        else DST = unl_n + ((size_t)(b * 2500 + cmpw[n - 125])) * 64; }
        COLPTR(0, colp0) COLPTR(1, colp1) COLPTR(2, colp2) COLPTR(3, colp3)
#undef COLPTR
    }
    __syncthreads();

    float acc[5][4];
#pragma unroll
    for (int i = 0; i < 5; ++i)
#pragma unroll
        for (int j = 0; j < 4; ++j) acc[i][j] = 0.f;

    const float* qbase = &qls[ty * 5 * 64];
    for (int cg = 0; cg < 16; ++cg) {
        float4 cv0 = *(const float4*)(colp0 + cg * 4);
        float4 cv1 = *(const float4*)(colp1 + cg * 4);
        float4 cv2 = *(const float4*)(colp2 + cg * 4);
        float4 cv3 = *(const float4*)(colp3 + cg * 4);
#pragma unroll
        for (int i = 0; i < 5; ++i) {
            float4 qv = *(const float4*)(qbase + i * 64 + cg * 4);  // broadcast
            acc[i][0] = fmaf(cv0.x, qv.x, fmaf(cv0.y, qv.y, fmaf(cv0.z, qv.z, fmaf(cv0.w, qv.w, acc[i][0]))));
            acc[i][1] = fmaf(cv1.x, qv.x, fmaf(cv1.y, qv.y, fmaf(cv1.z, qv.z, fmaf(cv1.w, qv.w, acc[i][1]))));
            acc[i][2] = fmaf(cv2.x, qv.x, fmaf(cv2.y, qv.y, fmaf(cv2.z, qv.z, fmaf(cv2.w, qv.w, acc[i][2]))));
            acc[i][3] = fmaf(cv3.x, qv.x, fmaf(cv3.y, qv.y, fmaf(cv3.z, qv.z, fmaf(cv3.w, qv.w, acc[i][3]))));
        }
    }

    // store (s+1)*0.5 to simb, 4 cols per b128 write (conflict-free)
#pragma unroll
    for (int i = 0; i < 5; ++i) {
        float4 sv;
        sv.x = (acc[i][0] + 1.0f) * 0.5f;
        sv.y = (acc[i][1] + 1.0f) * 0.5f;
        sv.z = (acc[i][2] + 1.0f) * 0.5f;
        sv.w = (acc[i][3] + 1.0f) * 0.5f;
        *(float4*)&simb[(ty * 5 + i) * 260 + col0] = sv;
    }
    __syncthreads();

    // per-col argmax over mq (ascending mq, strict > = first-tie)
    if (tid < 256) {
        int col = tid;
        if (col < cw) {
            float cmax = NEGINF; int cam = 0;
#pragma unroll
            for (int mq = 0; mq < 25; ++mq) {
                float s = simb[mq * 260 + col];
                if (s > cmax) { cmax = s; cam = mq; }
            }
            amaxg[(size_t)bq * 3200 + (wb + col)] = (unsigned char)cam;
        }
    }
    // per-mq best over cols: 10 groups x 25 cols (ascending, strict >)
    if (tid < 250) {
        int rg = tid / 25, rq = tid % 25;
        float bv1 = NEGINF; int bp1 = 0x7fffffff;
        int base = rg * 25;
        for (int i = 0; i < 25; ++i) {
            int col = base + i;
            if (col < cw) {
                float s = simb[rq * 260 + col];
                if (s > bv1) { bv1 = s; bp1 = ((w * 2625 + col) << 12) | (wb + col); }
            }
        }
        redv[rg][rq] = bv1; redp[rg][rq] = bp1;
    }
    __syncthreads();
    if (tid < 25) {
        float v = redv[0][tid]; int p = redp[0][tid];
#pragma unroll
        for (int g = 1; g < 10; ++g)
            if (redv[g][tid] > v) { v = redv[g][tid]; p = redp[g][tid]; }  // ascending groups
        if (L > cntw) {   // phantom zero-columns: sim == 0.5 at col 125+cntw
            int pp = ((w * 2625 + 125 + cntw) << 12) | 0xFFF;
            if (0.5f > v || (0.5f == v && pp < p)) { v = 0.5f; p = pp; }
        }
        size_t o = ((size_t)bq * 5 + w) * 25 + tid;
        bvg[o] = v; bpg[o] = p;
    }
}

// ============================================================
// Kernel CE: merge 5 way-partials per (bq,mq), mutual mask, row loss,
// atomicAdd into d_out. 300 blocks x 64.
// ============================================================
__global__ __launch_bounds__(64) void kce(
    const float* __restrict__ bvg, const int* __restrict__ bpg,
    const unsigned char* __restrict__ amaxg, const int* __restrict__ qy,
    float* __restrict__ out)
{
    int bq = blockIdx.x;
    int tid = threadIdx.x;
    __shared__ float qmask[25];
    __shared__ float lg[5];
    if (tid < 25) {
        float v = NEGINF; int p = 0x7fffffff;
#pragma unroll
        for (int w = 0; w < 5; ++w) {
            size_t o = ((size_t)bq * 5 + w) * 25 + tid;
            float v2 = bvg[o]; int p2 = bpg[o];
            if (v2 > v || (v2 == v && p2 < p)) { v = v2; p = p2; }
        }
        int pos = p & 0xFFF;
        int g = (pos == 0xFFF) ? 0 : (int)amaxg[(size_t)bq * 3200 + pos];
        qmask[tid] = (g == tid) ? 1.0f : 0.0f;
    }
    __syncthreads();
    if (tid < 5) {
        float s = 0.f;
#pragma unroll
        for (int mq = 0; mq < 25; ++mq)
            s += bvg[((size_t)bq * 5 + tid) * 25 + mq] * qmask[mq];
        lg[tid] = s;
    }
    __syncthreads();
    if (tid == 0) {
        int y = qy[bq];
        float mx = lg[0];
#pragma unroll
        for (int w = 1; w < 5; ++w) mx = fmaxf(mx, lg[w]);
        float se = 0.f;
#pragma unroll
        for (int w = 0; w < 5; ++w) se += expf(lg[w] - mx);
        float loss = -(lg[y] - mx - logf(se));
        atomicAdd(out, loss * (1.0f / 300.0f));
    }
}

// ============================================================
extern "C" void kernel_launch(void* const* d_in, const int* in_sizes, int n_in,
                              void* d_out, int out_size, void* d_ws, size_t ws_size,
                              hipStream_t stream)
{
    const float* sup = (const float*)d_in[0];
    const float* qry = (const float*)d_in[2];
    const int*   qy  = (const int*)d_in[3];
    const float* unl = (const float*)d_in[4];

    float* ws    = (float*)d_ws;
    float* unl_n = ws + OF_UNL;
    float* sup_n = ws + OF_SUP;
    float* supT  = ws + OF_SUPT;
    float* qt    = ws + OF_QT;
    float* rowv  = ws + OF_ROWV;
    int*   rowi  = (int*)(ws + OF_ROWI);
    float* colvi = ws + OF_CVI;
    int*   cmp   = (int*)(ws + OF_CMP);
    int*   cntg  = (int*)(ws + OF_CNT);
    int*   unear = (int*)(ws + OF_UNEAR);
    int*   snear = (int*)(ws + OF_SNEAR);
    float* bvg   = ws + OF_BV;
    int*   bpg   = (int*)(ws + OF_BP);
    unsigned char* amaxg = (unsigned char*)(ws + OF_AMX);

    hipMemsetAsync(d_out, 0, sizeof(float), stream);

    hipLaunchKernelGGL(knorm, dim3(1250), dim3(256), 0, stream,
                       sup, qry, unl, unl_n, sup_n, supT, qt);
    hipLaunchKernelGGL(kb, dim3(1600), dim3(256), 0, stream,
                       unl_n, supT, rowv, rowi, colvi);
    hipLaunchKernelGGL(kmerge, dim3(49), dim3(256), 0, stream,
                       rowv, rowi, colvi, unear, snear);
    hipLaunchKernelGGL(kcmp, dim3(20), dim3(256), 0, stream,
                       unear, snear, cmp, cntg);
    hipLaunchKernelGGL(kc1, dim3(1500), dim3(320), 0, stream,
                       qt, sup_n, unl_n, cmp, cntg, bvg, bpg, amaxg);
    hipLaunchKernelGGL(kce, dim3(300), dim3(64), 0, stream,
                       bvg, bpg, amaxg, qy, (float*)d_out);
}

// Round 12
// 183.027 us; speedup vs baseline: 1.4009x; 1.2071x over previous
//
#include <hip/hip_runtime.h>

#define NEGINF (-1e30f)

// ---------------- problem constants ----------------
// b=4, c=64, h=w=5, q=75, u=100, N_WAY=5, K_SHOT=5
// M_s = 125 (per way), M_u = 2500, M_q = 25, M_tot = 2625
// ---------------- workspace layout (float units) ----------------
constexpr size_t OF_UNL  = 0;                              // [4][2500][64]
constexpr size_t OF_COLT = OF_UNL  + (size_t)4*2500*64;    // [20bw][64c][256col] channel-major columns
constexpr size_t OF_QT   = OF_COLT + (size_t)20*64*256;    // [300][25mq][64c]
constexpr size_t OF_ROWV = OF_QT   + (size_t)300*64*25;    // [4][5][8ck][2500] f
constexpr size_t OF_ROWI = OF_ROWV + (size_t)4*5*8*2500;   // [4][5][8ck][2500] i
constexpr size_t OF_CVI  = OF_ROWI + (size_t)4*5*8*2500;   // [4][5][125][20][2]
constexpr size_t OF_CMP  = OF_CVI  + (size_t)4*5*125*20*2; // [4][5][2500] i
constexpr size_t OF_CNT  = OF_CMP  + (size_t)4*5*2500;     // [20] i
constexpr size_t OF_UNEAR= OF_CNT  + 20;                   // [4][2500] i
constexpr size_t OF_SNEAR= OF_UNEAR+ 10000;                // [4][625]  i
constexpr size_t OF_BV   = OF_SNEAR+ 2500;                 // [300][5][25] f
constexpr size_t OF_BP   = OF_BV   + 37500;                // [300][5][25] i
constexpr size_t OF_AMX  = OF_BP   + 37500;                // [300][3200] u8

// ============================================================
// Kernel A: L2-normalize into ws layouts.
// unl -> unl_n[b][m][64] (row-major); support -> colT[bw][c][n]
// (channel-major, cols 0..124); query -> qt[bq][mq][64].
// ============================================================
__global__ __launch_bounds__(256) void knorm(
    const float* __restrict__ sup, const float* __restrict__ qry,
    const float* __restrict__ unl,
    float* __restrict__ unl_n, float* __restrict__ colT,
    float* __restrict__ qt)
{
    int gid = blockIdx.x * 256 + threadIdx.x;
    int loc = gid >> 4;
    int sub = gid & 15;
    if (loc >= 20000) return;

    const float* src;
    float* dst1; int dstr1;

    if (loc < 10000) {
        int b = loc / 2500, m = loc % 2500;
        int u = m / 25, hw = m % 25;
        src  = unl + ((size_t)(b*100 + u) * 64) * 25 + hw;
        dst1 = unl_n + (size_t)loc * 64; dstr1 = 1;
    } else if (loc < 12500) {
        int idx = loc - 10000;
        int b = idx / 625, r = idx % 625;
        int w = r / 125,  n = r % 125;
        int shot = n / 25, hw = n % 25;
        src  = sup + ((size_t)(b*25 + w*5 + shot) * 64) * 25 + hw;
        dst1 = colT + ((size_t)(b*5 + w) * 64) * 256 + n; dstr1 = 256;
    } else {
        int idx = loc - 12500;
        int bq = idx / 25, mq = idx % 25;
        src  = qry + ((size_t)bq * 64) * 25 + mq;
        dst1 = qt + ((size_t)bq * 25 + mq) * 64; dstr1 = 1;
    }

    float v[4]; float ss = 0.f;
    int c0 = sub * 4;
#pragma unroll
    for (int j = 0; j < 4; ++j) { v[j] = src[(size_t)(c0 + j) * 25]; ss += v[j] * v[j]; }
#pragma unroll
    for (int msk = 1; msk < 16; msk <<= 1) ss += __shfl_xor(ss, msk);
    float sc = 1.f / fmaxf(sqrtf(ss), 1e-12f);
#pragma unroll
    for (int j = 0; j < 4; ++j)
        dst1[(size_t)(c0 + j) * dstr1] = v[j] * sc;
}

// ============================================================
// Kernel B: u2s pass. 1600 blocks x 256 threads.
// (structure unchanged; support now read from colT stride 256)
// ============================================================
__global__ __launch_bounds__(256) void kb(
    const float* __restrict__ unl_n, const float* __restrict__ colT,
    float* __restrict__ rowv, int* __restrict__ rowi, float* __restrict__ colvi)
{
    int bid = blockIdx.x;
    int nc = bid & 3;
    int mb = (bid >> 2) % 20;
    int bw = bid / 80;               // b*5+w
    int b  = bw / 5;
    int tid = threadIdx.x;
    int lane = tid & 63, wv = tid >> 6;

    __shared__ float uls[128 * 65];
    __shared__ float sls[64 * 36];
    __shared__ float sv_[4][32];
    __shared__ int   si_[4][32];

    int m0 = mb * 128;
    int n0 = nc * 32;

    for (int i = tid; i < 128 * 16; i += 256) {
        int row = i >> 4, c4 = (i & 15) * 4;
        int m = m0 + row;
        float4 x = make_float4(0.f, 0.f, 0.f, 0.f);
        if (m < 2500) x = *(const float4*)(unl_n + ((size_t)(b * 2500 + m)) * 64 + c4);
        uls[row * 65 + c4 + 0] = x.x;
        uls[row * 65 + c4 + 1] = x.y;
        uls[row * 65 + c4 + 2] = x.z;
        uls[row * 65 + c4 + 3] = x.w;
    }
    {
        int c = tid >> 2, q = tid & 3;
        const float* sp = colT + ((size_t)bw * 64 + c) * 256 + n0 + q * 8;
        float4 a = *(const float4*)sp;
        float4 d4 = *(const float4*)(sp + 4);
        float* d = &sls[c * 36 + q * 8];
        d[0] = a.x; d[1] = a.y; d[2] = a.z; d[3] = a.w;
        d[4] = d4.x; d[5] = d4.y; d[6] = d4.z; d[7] = d4.w;
    }
    __syncthreads();

    int ml = tid & 127;
    int m  = m0 + ml;
    int nh = tid >> 7;
    int nbase = nh * 16;
    int nn_total = (125 - n0) < 32 ? (125 - n0) : 32;
    const float* myrow = &uls[ml * 65];

    float acc[16];
#pragma unroll
    for (int j = 0; j < 16; ++j) acc[j] = 0.f;

    for (int c = 0; c < 64; ++c) {
        float uv = myrow[c];
        const float4* sr = (const float4*)&sls[c * 36 + nbase];
        float4 s0 = sr[0], s1 = sr[1], s2 = sr[2], s3 = sr[3];
        acc[0]  = fmaf(uv, s0.x, acc[0]);  acc[1]  = fmaf(uv, s0.y, acc[1]);
        acc[2]  = fmaf(uv, s0.z, acc[2]);  acc[3]  = fmaf(uv, s0.w, acc[3]);
        acc[4]  = fmaf(uv, s1.x, acc[4]);  acc[5]  = fmaf(uv, s1.y, acc[5]);
        acc[6]  = fmaf(uv, s1.z, acc[6]);  acc[7]  = fmaf(uv, s1.w, acc[7]);
        acc[8]  = fmaf(uv, s2.x, acc[8]);  acc[9]  = fmaf(uv, s2.y, acc[9]);
        acc[10] = fmaf(uv, s2.z, acc[10]); acc[11] = fmaf(uv, s2.w, acc[11]);
        acc[12] = fmaf(uv, s3.x, acc[12]); acc[13] = fmaf(uv, s3.y, acc[13]);
        acc[14] = fmaf(uv, s3.z, acc[14]); acc[15] = fmaf(uv, s3.w, acc[15]);
    }

    int nnloc = nn_total - nbase;
    nnloc = nnloc < 0 ? 0 : (nnloc > 16 ? 16 : nnloc);
    float rbv = NEGINF; int rbi = 0;
    for (int j = 0; j < nnloc; ++j)
        if (acc[j] > rbv) { rbv = acc[j]; rbi = n0 + nbase + j; }
    if (m < 2500) {
        int ck = nc * 2 + nh;
        rowv[((size_t)bw * 8 + ck) * 2500 + m] = rbv;
        rowi[((size_t)bw * 8 + ck) * 2500 + m] = rbi;
    }

#pragma unroll
    for (int j = 0; j < 16; ++j) {
        float v = (m < 2500 && (nbase + j) < nn_total) ? acc[j] : NEGINF;
        float vm = v;
#pragma unroll
        for (int s2 = 1; s2 < 64; s2 <<= 1) vm = fmaxf(vm, __shfl_xor(vm, s2));
        unsigned long long msk = __ballot(v == vm);
        int first = __ffsll((unsigned long long)msk) - 1;
        if (lane == 0) { sv_[wv][nbase + j] = vm; si_[wv][nbase + j] = m0 + (wv & 1) * 64 + first; }
    }
    __syncthreads();
    if (tid < nn_total) {
        int w0 = (tid < 16) ? 0 : 2;
        float v = sv_[w0][tid];     int vi = si_[w0][tid];
        float v2 = sv_[w0 + 1][tid]; int i2 = si_[w0 + 1][tid];
        if (v2 > v || (v2 == v && i2 < vi)) { v = v2; vi = i2; }
        float* cv = colvi + ((((size_t)bw) * 125 + (n0 + tid)) * 20 + mb) * 2;
        cv[0] = v; ((int*)cv)[1] = vi;
    }
}

// ============================================================
// Kernel M: merge row partials -> unear, col partials -> snear.
// ============================================================
__global__ __launch_bounds__(256) void kmerge(
    const float* __restrict__ rowv, const int* __restrict__ rowi,
    const float* __restrict__ colvi,
    int* __restrict__ unear, int* __restrict__ snear)
{
    int it = blockIdx.x * 256 + threadIdx.x;
    if (it < 10000) {
        int b = it / 2500, m = it % 2500;
        float bv = NEGINF; int bi = 0;
#pragma unroll
        for (int w = 0; w < 5; ++w) {
#pragma unroll
            for (int ck = 0; ck < 8; ++ck) {
                size_t o = (((size_t)(b * 5 + w)) * 8 + ck) * 2500 + m;
                float v = rowv[o];
                if (v > bv) { bv = v; bi = w * 125 + rowi[o]; }
            }
        }
        unear[it] = bi;
    } else if (it < 12500) {
        int idx = it - 10000;
        const float* p = colvi + (size_t)idx * 40;
        float bv = NEGINF; int bi = 0x7fffffff;
        for (int mb2 = 0; mb2 < 20; ++mb2) {
            float v = p[mb2 * 2]; int vi = ((const int*)p)[mb2 * 2 + 1];
            if (v > bv || (v == bv && vi < bi)) { bv = v; bi = vi; }
        }
        snear[idx] = bi;
    }
}

// ============================================================
// Kernel P: mutual-NN mask + stable compaction + GATHER into colT
// (channel-major, cols 125..125+cnt). 20 blocks x 256.
// cnt <= 125 structurally (injective into the way's support slots).
// ============================================================
__global__ __launch_bounds__(256) void kcmp(
    const int* __restrict__ unear, const int* __restrict__ snear,
    const float* __restrict__ unl_n,
    int* __restrict__ cmp, int* __restrict__ cntg, float* __restrict__ colT)
{
    int p = blockIdx.x;
    int b = p / 5, way = p % 5;
    int tid = threadIdx.x, lane = tid & 63, wv = tid >> 6;
    __shared__ unsigned long long masks[40];
    __shared__ int base[40];
    __shared__ int tot_s;

    for (int ch = wv; ch < 40; ch += 4) {
        int m = ch * 64 + lane;
        bool ok = false;
        if (m < 2500) {
            int un = unear[b * 2500 + m];
            ok = (un / 125 == way) && (snear[b * 625 + un] == m);
        }
        unsigned long long msk = __ballot(ok ? 1 : 0);
        if (lane == 0) masks[ch] = msk;
    }
    __syncthreads();
    if (tid == 0) {
        int s = 0;
        for (int ch = 0; ch < 40; ++ch) { base[ch] = s; s += __popcll(masks[ch]); }
        cntg[p] = s; tot_s = s;
    }
    __syncthreads();
    for (int ch = wv; ch < 40; ch += 4) {
        unsigned long long msk = masks[ch];
        if ((msk >> lane) & 1ull) {
            int pre = __popcll(msk & ((1ull << lane) - 1ull));
            cmp[(size_t)p * 2500 + base[ch] + pre] = ch * 64 + lane;
        }
    }
    __syncthreads();
    // gather compacted columns channel-major: colT[p][c][125+i]
    int tot = tot_s;
    for (int t = tid; t < tot * 64; t += 256) {
        int i = t >> 6, c = t & 63;          // consecutive tid -> consecutive c: coalesced reads
        int m = cmp[(size_t)p * 2500 + i];
        colT[((size_t)p * 64 + c) * 256 + 125 + i] =
            unl_n[((size_t)(b * 2500 + m)) * 64 + c];
    }
}

// ============================================================
// Kernel C1: query similarity. One block (320 thr = 5 waves) per
// (bq, way). Round-11 fix: columns are CHANNEL-MAJOR in colT, so
// lane l's load colT[bw][c][4l] is contiguous across lanes -> one
// coalesced 1KB transaction per VMEM instr (r11 was 64 cache lines
// per instr -> request-issue bound, VALUBusy 17%).
// Per c-quad: 4 coalesced VMEM + 5 q LDS broadcasts + 80 FMA.
// Epilogue: per-wave partial argmaxes in small LDS; exact first-tie
// semantics (ascending mq across waves; min-pack among val ties).
// ============================================================
__global__ __launch_bounds__(320) void kc1(
    const float* __restrict__ qt, const float* __restrict__ colT,
    const int* __restrict__ cntg,
    float* __restrict__ bvg, int* __restrict__ bpg,
    unsigned char* __restrict__ amaxg)
{
    int bid = blockIdx.x;
    int w = bid % 5, bq = bid / 5;
    int b = bq / 75;
    int bw = b * 5 + w;
    int tid = threadIdx.x;
    int lane = tid & 63, ty = tid >> 6;

    int L = 0;
#pragma unroll
    for (int i = 0; i < 20; ++i) { int v = cntg[i]; L = L > v ? L : v; }
    int cntw = 0, wb = 0;
#pragma unroll
    for (int w2 = 0; w2 < 5; ++w2) {
        int c2 = cntg[b * 5 + w2];
        if (w2 < w) wb += 125 + c2;
        if (w2 == w) cntw = c2;
    }
    int cw = 125 + cntw;    // 125..250 <= 256

    __shared__ float qls[1600];          // [mq][c]
    __shared__ float amv[5][256];
    __shared__ unsigned char ami[5][256];
    __shared__ float redv[5][5];
    __shared__ int   redp[5][5];

    for (int i = tid; i < 1600; i += 320) qls[i] = qt[(size_t)bq * 1600 + i];
    __syncthreads();

    const float* cbase = colT + ((size_t)bw * 64) * 256 + lane * 4;
    float acc[5][4];
#pragma unroll
    for (int i = 0; i < 5; ++i)
#pragma unroll
        for (int j = 0; j < 4; ++j) acc[i][j] = 0.f;

    for (int c4 = 0; c4 < 16; ++c4) {
        float4 cv0 = *(const float4*)(cbase + (size_t)(c4 * 4 + 0) * 256);
        float4 cv1 = *(const float4*)(cbase + (size_t)(c4 * 4 + 1) * 256);
        float4 cv2 = *(const float4*)(cbase + (size_t)(c4 * 4 + 2) * 256);
        float4 cv3 = *(const float4*)(cbase + (size_t)(c4 * 4 + 3) * 256);
#pragma unroll
        for (int i = 0; i < 5; ++i) {
            float4 qv = *(const float4*)&qls[(ty * 5 + i) * 64 + c4 * 4];  // broadcast
            acc[i][0] = fmaf(cv0.x, qv.x, fmaf(cv1.x, qv.y, fmaf(cv2.x, qv.z, fmaf(cv3.x, qv.w, acc[i][0]))));
            acc[i][1] = fmaf(cv0.y, qv.x, fmaf(cv1.y, qv.y, fmaf(cv2.y, qv.z, fmaf(cv3.y, qv.w, acc[i][1]))));
            acc[i][2] = fmaf(cv0.z, qv.x, fmaf(cv1.z, qv.y, fmaf(cv2.z, qv.z, fmaf(cv3.z, qv.w, acc[i][2]))));
            acc[i][3] = fmaf(cv0.w, qv.x, fmaf(cv1.w, qv.y, fmaf(cv2.w, qv.z, fmaf(cv3.w, qv.w, acc[i][3]))));
        }
    }

    // sim transform + local per-col argmax over this wave's 5 mqs
    float cmax[4]; int cam[4];
#pragma unroll
    for (int j = 0; j < 4; ++j) { cmax[j] = NEGINF; cam[j] = 0; }
#pragma unroll
    for (int i = 0; i < 5; ++i)
#pragma unroll
        for (int j = 0; j < 4; ++j) {
            float s = (acc[i][j] + 1.0f) * 0.5f;
            acc[i][j] = s;
            if (s > cmax[j]) { cmax[j] = s; cam[j] = ty * 5 + i; }  // ascending i = first-tie
        }
    *(float4*)&amv[ty][lane * 4] = make_float4(cmax[0], cmax[1], cmax[2], cmax[3]);
    {
        unsigned int pk = (unsigned)cam[0] | ((unsigned)cam[1] << 8) |
                          ((unsigned)cam[2] << 16) | ((unsigned)cam[3] << 24);
        ((unsigned int*)&ami[ty][0])[lane] = pk;
    }

    // per-mq best over own 4 cols (ascending col, strict >), then lane-reduce
#pragma unroll
    for (int i = 0; i < 5; ++i) {
        float bv = NEGINF; int bp = 0x7fffffff;
#pragma unroll
        for (int j = 0; j < 4; ++j) {
            int n = lane * 4 + j;
            if (n < cw) {
                float s = acc[i][j];
                if (s > bv) { bv = s; bp = ((w * 2625 + n) << 12) | (wb + n); }
            }
        }
        float vm = bv;
#pragma unroll
        for (int s2 = 1; s2 < 64; s2 <<= 1) vm = fmaxf(vm, __shfl_xor(vm, s2));
        int p = (bv == vm) ? bp : 0x7fffffff;
#pragma unroll
        for (int s2 = 1; s2 < 64; s2 <<= 1) p = min(p, __shfl_xor(p, s2));
        if (lane == 0) { redv[ty][i] = vm; redp[ty][i] = p; }
    }
    __syncthreads();

    // merge per-col argmax across 5 waves (ascending ty = ascending mq)
    if (tid < 256) {
        int col = tid;
        if (col < cw) {
            float v = amv[0][col]; int g = ami[0][col];
#pragma unroll
            for (int t2 = 1; t2 < 5; ++t2)
                if (amv[t2][col] > v) { v = amv[t2][col]; g = ami[t2][col]; }
            amaxg[(size_t)bq * 3200 + (wb + col)] = (unsigned char)g;
        }
    }
    // per-mq result + phantom
    if (tid < 25) {
        int t2 = tid / 5, i = tid % 5;       // mq = t2*5 + i = tid
        float v = redv[t2][i]; int p = redp[t2][i];
        if (L > cntw) {   // phantom zero-columns: sim == 0.5, first at col 125+cntw
            int pp = ((w * 2625 + 125 + cntw) << 12) | 0xFFF;
            if (0.5f > v || (0.5f == v && pp < p)) { v = 0.5f; p = pp; }
        }
        size_t o = ((size_t)bq * 5 + w) * 25 + tid;
        bvg[o] = v; bpg[o] = p;
    }
}

// ============================================================
// Kernel CE: merge 5 way-partials per (bq,mq), mutual mask, row loss,
// atomicAdd into d_out. 300 blocks x 64.
// ============================================================
__global__ __launch_bounds__(64) void kce(
    const float* __restrict__ bvg, const int* __restrict__ bpg,
    const unsigned char* __restrict__ amaxg, const int* __restrict__ qy,
    float* __restrict__ out)
{
    int bq = blockIdx.x;
    int tid = threadIdx.x;
    __shared__ float qmask[25];
    __shared__ float lg[5];
    if (tid < 25) {
        float v = NEGINF; int p = 0x7fffffff;
#pragma unroll
        for (int w = 0; w < 5; ++w) {
            size_t o = ((size_t)bq * 5 + w) * 25 + tid;
            float v2 = bvg[o]; int p2 = bpg[o];
            if (v2 > v || (v2 == v && p2 < p)) { v = v2; p = p2; }
        }
        int pos = p & 0xFFF;
        int g = (pos == 0xFFF) ? 0 : (int)amaxg[(size_t)bq * 3200 + pos];
        qmask[tid] = (g == tid) ? 1.0f : 0.0f;
    }
    __syncthreads();
    if (tid < 5) {
        float s = 0.f;
#pragma unroll
        for (int mq = 0; mq < 25; ++mq)
            s += bvg[((size_t)bq * 5 + tid) * 25 + mq] * qmask[mq];
        lg[tid] = s;
    }
    __syncthreads();
    if (tid == 0) {
        int y = qy[bq];
        float mx = lg[0];
#pragma unroll
        for (int w = 1; w < 5; ++w) mx = fmaxf(mx, lg[w]);
        float se = 0.f;
#pragma unroll
        for (int w = 0; w < 5; ++w) se += expf(lg[w] - mx);
        float loss = -(lg[y] - mx - logf(se));
        atomicAdd(out, loss * (1.0f / 300.0f));
    }
}

// ============================================================
extern "C" void kernel_launch(void* const* d_in, const int* in_sizes, int n_in,
                              void* d_out, int out_size, void* d_ws, size_t ws_size,
                              hipStream_t stream)
{
    const float* sup = (const float*)d_in[0];
    const float* qry = (const float*)d_in[2];
    const int*   qy  = (const int*)d_in[3];
    const float* unl = (const float*)d_in[4];

    float* ws    = (float*)d_ws;
    float* unl_n = ws + OF_UNL;
    float* colT  = ws + OF_COLT;
    float* qt    = ws + OF_QT;
    float* rowv  = ws + OF_ROWV;
    int*   rowi  = (int*)(ws + OF_ROWI);
    float* colvi = ws + OF_CVI;
    int*   cmp   = (int*)(ws + OF_CMP);
    int*   cntg  = (int*)(ws + OF_CNT);
    int*   unear = (int*)(ws + OF_UNEAR);
    int*   snear = (int*)(ws + OF_SNEAR);
    float* bvg   = ws + OF_BV;
    int*   bpg   = (int*)(ws + OF_BP);
    unsigned char* amaxg = (unsigned char*)(ws + OF_AMX);

    hipMemsetAsync(d_out, 0, sizeof(float), stream);

    hipLaunchKernelGGL(knorm, dim3(1250), dim3(256), 0, stream,
                       sup, qry, unl, unl_n, colT, qt);
    hipLaunchKernelGGL(kb, dim3(1600), dim3(256), 0, stream,
                       unl_n, colT, rowv, rowi, colvi);
    hipLaunchKernelGGL(kmerge, dim3(49), dim3(256), 0, stream,
                       rowv, rowi, colvi, unear, snear);
    hipLaunchKernelGGL(kcmp, dim3(20), dim3(256), 0, stream,
                       unear, snear, unl_n, cmp, cntg, colT);
    hipLaunchKernelGGL(kc1, dim3(1500), dim3(320), 0, stream,
                       qt, colT, cntg, bvg, bpg, amaxg);
    hipLaunchKernelGGL(kce, dim3(300), dim3(64), 0, stream,
                       bvg, bpg, amaxg, qy, (float*)d_out);
}